// Round 3
// baseline (247.809 us; speedup 1.0000x reference)
//
#include <hip/hip_runtime.h>
#include <hip/hip_bf16.h>

#define D_MODEL 1024
#define NHEAD   16
#define HDK     64
#define SEQ     2048
#define BATCH   2
#define BS      (BATCH * SEQ)

typedef __attribute__((ext_vector_type(8))) short bf16x8;
typedef __attribute__((ext_vector_type(4))) float f32x4;

// dynamic work-queue counter for attn (init by cast_act each launch)
__device__ unsigned g_attn_cnt;

__device__ __forceinline__ unsigned short f2bf(float f) {
    unsigned u = __builtin_bit_cast(unsigned, f);
    u += 0x7fffu + ((u >> 16) & 1u);          // round-to-nearest-even
    return (unsigned short)(u >> 16);
}

// pack hi16(x):hi16(y) -> (hi16(y)<<16)|hi16(x) with one v_perm_b32 (truncation)
__device__ __forceinline__ unsigned pack_hi(float x, float y) {
    return __builtin_amdgcn_perm(__builtin_bit_cast(unsigned, y),
                                 __builtin_bit_cast(unsigned, x), 0x07060302u);
}

// guaranteed-native 2^x (exp2f() can lower to a slow libcall)
__device__ __forceinline__ float exp2_fast(float x) {
    float r;
    asm("v_exp_f32 %0, %1" : "=v"(r) : "v"(x));
    return r;
}

typedef const void __attribute__((address_space(1))) gas_void;
typedef void __attribute__((address_space(3))) las_void;

__device__ __forceinline__ void gll16(const void* g, void* l) {
    __builtin_amdgcn_global_load_lds((gas_void*)g, (las_void*)l, 16, 0, 0);
}

// ---------------------------------------------------------------------------
// fp32 -> bf16 casts
// ---------------------------------------------------------------------------
__device__ __forceinline__ void cast_body(const float* __restrict__ src,
                                          unsigned short* __restrict__ dst, int i) {
    const float4* p = (const float4*)src + (size_t)i * 2;
    float4 a = p[0], b = p[1];
    ushort4 lo = make_ushort4(f2bf(a.x), f2bf(a.y), f2bf(a.z), f2bf(a.w));
    ushort4 hi = make_ushort4(f2bf(b.x), f2bf(b.y), f2bf(b.z), f2bf(b.w));
    ushort4* q = (ushort4*)dst + (size_t)i * 2;
    q[0] = lo; q[1] = hi;
}

__global__ __launch_bounds__(256)
void cast_act(const float* a, const float* b, const float* c,
              unsigned short* oa, unsigned short* ob, unsigned short* oc, int n8) {
    if (blockIdx.x == 0 && blockIdx.y == 0 && threadIdx.x == 0)
        g_attn_cnt = 1024;                  // attn blocks 0..1023 take items 0..1023 statically
    int i = blockIdx.x * 256 + threadIdx.x;
    if (i >= n8) return;
    const float* s = blockIdx.y == 0 ? a : blockIdx.y == 1 ? b : c;
    unsigned short* d = blockIdx.y == 0 ? oa : blockIdx.y == 1 ? ob : oc;
    cast_body(s, d, i);
}

__global__ __launch_bounds__(256)
void cast_wt(const float* a, const float* b, const float* c, const float* dd,
             unsigned short* oa, unsigned short* ob, unsigned short* oc, unsigned short* od, int n8) {
    int i = blockIdx.x * 256 + threadIdx.x;
    if (i >= n8) return;
    const float* s = blockIdx.y == 0 ? a : blockIdx.y == 1 ? b : blockIdx.y == 2 ? c : dd;
    unsigned short* d = blockIdx.y == 0 ? oa : blockIdx.y == 1 ? ob : blockIdx.y == 2 ? oc : od;
    cast_body(s, d, i);
}

// ---------------------------------------------------------------------------
// GEMM K-loop, BM=128 BN=128 BK=64, 256 thr, wave -> 64x64 quadrant.
// ---------------------------------------------------------------------------
__device__ __forceinline__ void gemm_kloop128(const unsigned short* __restrict__ X,
                                              const unsigned short* __restrict__ W,
                                              unsigned short* As, unsigned short* Bs,
                                              int bm, int bn, f32x4 acc[4][4]) {
    const int t    = threadIdx.x;
    const int w    = t >> 6;
    const int L    = t & 63;
    const int quad = L >> 4;
    const int lm   = L & 15;
    const int r8   = L >> 3;
    const int sl   = L & 7;
    const int xcol = ((sl ^ r8) & 7) * 8;
    const int wr   = (w >> 1) * 64;
    const int wc   = (w & 1) * 64;

    for (int kt = 0; kt < D_MODEL; kt += 64) {
        __syncthreads();
        #pragma unroll
        for (int i = 0; i < 4; ++i) {
            int c = w * 4 + i;
            gll16(X + (size_t)(bm + c * 8 + r8) * D_MODEL + kt + xcol, &As[c * 512]);
        }
        #pragma unroll
        for (int i = 0; i < 4; ++i) {
            int c = w * 4 + i;
            gll16(W + (size_t)(bn + c * 8 + r8) * D_MODEL + kt + xcol, &Bs[c * 512]);
        }
        __syncthreads();

        #pragma unroll
        for (int ch = 0; ch < 2; ++ch) {
            bf16x8 af[4], bfr[4];
            #pragma unroll
            for (int ms = 0; ms < 4; ++ms) {
                int row = wr + ms * 16 + lm;
                af[ms] = *(const bf16x8*)&As[row * 64 + (((ch * 4 + quad) ^ (row & 7)) * 8)];
            }
            #pragma unroll
            for (int ns = 0; ns < 4; ++ns) {
                int row = wc + ns * 16 + lm;
                bfr[ns] = *(const bf16x8*)&Bs[row * 64 + (((ch * 4 + quad) ^ (row & 7)) * 8)];
            }
            #pragma unroll
            for (int ms = 0; ms < 4; ++ms)
                #pragma unroll
                for (int ns = 0; ns < 4; ++ns)
                    acc[ms][ns] = __builtin_amdgcn_mfma_f32_16x16x32_bf16(
                        af[ms], bfr[ns], acc[ms][ns], 0, 0, 0);
        }
    }
}

// BM=128 BN=64 variant (more blocks for the small out_gemm)
__device__ __forceinline__ void gemm_kloop64(const unsigned short* __restrict__ X,
                                             const unsigned short* __restrict__ W,
                                             unsigned short* As, unsigned short* Bs,
                                             int bm, int bn, f32x4 acc[2][4]) {
    const int t    = threadIdx.x;
    const int w    = t >> 6;
    const int L    = t & 63;
    const int quad = L >> 4;
    const int lm   = L & 15;
    const int r8   = L >> 3;
    const int sl   = L & 7;
    const int xcol = ((sl ^ r8) & 7) * 8;

    for (int kt = 0; kt < D_MODEL; kt += 64) {
        __syncthreads();
        #pragma unroll
        for (int i = 0; i < 4; ++i) {
            int c = w * 4 + i;
            gll16(X + (size_t)(bm + c * 8 + r8) * D_MODEL + kt + xcol, &As[c * 512]);
        }
        #pragma unroll
        for (int i = 0; i < 2; ++i) {
            int c = w * 2 + i;
            gll16(W + (size_t)(bn + c * 8 + r8) * D_MODEL + kt + xcol, &Bs[c * 512]);
        }
        __syncthreads();

        #pragma unroll
        for (int ch = 0; ch < 2; ++ch) {
            bf16x8 af[2], bfr[4];
            #pragma unroll
            for (int ms = 0; ms < 2; ++ms) {
                int row = w * 32 + ms * 16 + lm;
                af[ms] = *(const bf16x8*)&As[row * 64 + (((ch * 4 + quad) ^ (row & 7)) * 8)];
            }
            #pragma unroll
            for (int ns = 0; ns < 4; ++ns) {
                int row = ns * 16 + lm;
                bfr[ns] = *(const bf16x8*)&Bs[row * 64 + (((ch * 4 + quad) ^ (row & 7)) * 8)];
            }
            #pragma unroll
            for (int ms = 0; ms < 2; ++ms)
                #pragma unroll
                for (int ns = 0; ns < 4; ++ns)
                    acc[ms][ns] = __builtin_amdgcn_mfma_f32_16x16x32_bf16(
                        af[ms], bfr[ns], acc[ms][ns], 0, 0, 0);
        }
    }
}

// ---------------------------------------------------------------------------
// Fused Q/K/V projections. z=0: Q (x 0.125*log2(e) -> exp2-domain softmax,
// row-major), z=1: K (row-major), z=2: V transposed per head.
// ---------------------------------------------------------------------------
__global__ __launch_bounds__(256, 3)
void proj_gemm(const unsigned short* __restrict__ qx, const unsigned short* __restrict__ kx,
               const unsigned short* __restrict__ vx, const unsigned short* __restrict__ wq,
               const unsigned short* __restrict__ wk, const unsigned short* __restrict__ wv,
               unsigned short* __restrict__ Qp, unsigned short* __restrict__ Kp,
               unsigned short* __restrict__ VT) {
    __shared__ __align__(16) unsigned short As[128 * 64];
    __shared__ __align__(16) unsigned short Bs[128 * 64];

    const int p = blockIdx.z;
    const unsigned short* X = p == 0 ? qx : p == 1 ? kx : vx;
    const unsigned short* W = p == 0 ? wq : p == 1 ? wk : wv;
    const int bm = blockIdx.y * 128, bn = blockIdx.x * 128;

    f32x4 acc[4][4];
    #pragma unroll
    for (int ms = 0; ms < 4; ++ms)
        #pragma unroll
        for (int ns = 0; ns < 4; ++ns)
            acc[ms][ns] = (f32x4){0.f, 0.f, 0.f, 0.f};

    gemm_kloop128(X, W, As, Bs, bm, bn, acc);

    const int t = threadIdx.x, w = t >> 6, L = t & 63, quad = L >> 4, lm = L & 15;
    const int wr = (w >> 1) * 64, wc = (w & 1) * 64;
    if (p == 2) {
        const int b    = bm >> 11;
        const int s_in = (bm & (SEQ - 1)) + wr;
        #pragma unroll
        for (int ms = 0; ms < 4; ++ms)
            #pragma unroll
            for (int ns = 0; ns < 4; ++ns) {
                int dg = bn + wc + ns * 16 + lm;
                int h  = dg >> 6, d = dg & 63;
                ushort4 pk = make_ushort4(f2bf(acc[ms][ns][0]), f2bf(acc[ms][ns][1]),
                                          f2bf(acc[ms][ns][2]), f2bf(acc[ms][ns][3]));
                *(ushort4*)&VT[((size_t)((b * NHEAD + h) * HDK + d)) * SEQ +
                               s_in + ms * 16 + quad * 4] = pk;
            }
    } else {
        unsigned short* Y = p == 0 ? Qp : Kp;
        // 0.125 * log2(e): softmax runs in exp2 domain (saves a v_mul per exp)
        const float scl = p == 0 ? 0.18033688011112042f : 1.0f;
        #pragma unroll
        for (int ms = 0; ms < 4; ++ms)
            #pragma unroll
            for (int ns = 0; ns < 4; ++ns)
                #pragma unroll
                for (int r = 0; r < 4; ++r)
                    Y[(size_t)(bm + wr + ms * 16 + quad * 4 + r) * D_MODEL +
                      bn + wc + ns * 16 + lm] = f2bf(acc[ms][ns][r] * scl);
    }
}

__global__ __launch_bounds__(256)
void out_gemm(const unsigned short* __restrict__ X, const unsigned short* __restrict__ W,
              float* __restrict__ Y) {
    __shared__ __align__(16) unsigned short As[128 * 64];
    __shared__ __align__(16) unsigned short Bs[64 * 64];
    const int bm = blockIdx.y * 128, bn = blockIdx.x * 64;

    f32x4 acc[2][4];
    #pragma unroll
    for (int ms = 0; ms < 2; ++ms)
        #pragma unroll
        for (int ns = 0; ns < 4; ++ns)
            acc[ms][ns] = (f32x4){0.f, 0.f, 0.f, 0.f};

    gemm_kloop64(X, W, As, Bs, bm, bn, acc);

    const int t = threadIdx.x, w = t >> 6, L = t & 63, quad = L >> 4, lm = L & 15;
    #pragma unroll
    for (int ms = 0; ms < 2; ++ms)
        #pragma unroll
        for (int ns = 0; ns < 4; ++ns)
            #pragma unroll
            for (int r = 0; r < 4; ++r)
                Y[(size_t)(bm + w * 32 + ms * 16 + quad * 4 + r) * D_MODEL +
                  bn + ns * 16 + lm] = acc[ms][ns][r];
}

// ---------------------------------------------------------------------------
// Flash attention, causal, S^T formulation.
// Round-3: persistent blocks + dynamic LPT work queue.
//  - 1024 persistent blocks, exactly 4 resident/CU (LDS = 40960 B = 160KiB/4,
//    VGPR<=128 via __launch_bounds__(256,4)) -> 4 independent chains per CU.
//  - work item = (b,h,qt), 2048 items sorted qt-DESCENDING (LPT). Block bid
//    starts on item bid (counter pre-set to 1024 by cast_act), then pops via
//    device-scope atomicAdd. Self-balancing regardless of block->CU mapping
//    (round 2's static decode put four same-qt blocks on one CU -> tail).
//  - item broadcast reuses the Ps slab (no extra LDS byte: 40961 would drop
//    residency to 3/CU). Broadcast read is consumed before the prologue
//    barrier; first Ps write of the next item is after it.
// ---------------------------------------------------------------------------
#define N_ITEMS 2048

__global__ __launch_bounds__(256, 4)
void attn_mfma(const unsigned short* __restrict__ Q, const unsigned short* __restrict__ K,
               const unsigned short* __restrict__ VT, unsigned short* __restrict__ A) {
    __shared__ __align__(16) unsigned short Ks[2][64 * 64];   // [buf][kv][d]  (xor-swizzled)
    __shared__ __align__(16) unsigned short Vs[2][64 * 64];   // [buf][d][kv]  (xor-swizzled)
    __shared__ __align__(16) unsigned short Ps[4][16 * 64];   // per-wave P^T slabs (swizzled)

    const int t    = threadIdx.x;
    const int w    = t >> 6;
    const int L    = t & 63;
    const int quad = L >> 4;
    const int lm   = L & 15;
    const int r8   = L >> 3;
    const int sl   = L & 7;
    const int xcol = (sl ^ r8) * 8;          // pre-swizzled global column for gll16

    int* const item_slot = (int*)&Ps[0][0];  // scratch between items (hazard-free, see hdr)

    int item = blockIdx.x;
    while (item < N_ITEMS) {
        // LPT decode: qt descending bands of 64 bh
        const int qt = 31 - (item >> 6);
        const int bh = item & 63;
        const int h  = bh & 15;
        const int b  = bh >> 4;

        const size_t hb   = (size_t)b * SEQ * D_MODEL + h * HDK;
        const size_t vrow = (size_t)(b * NHEAD + h) * HDK * SEQ;

        const unsigned short* kbase = K + hb;
        const unsigned short* vbase = VT + vrow;
        unsigned short* ps = &Ps[w][0];

        const int q0   = qt * 64;
        const int qrow = q0 + w * 16 + lm;

        // staging: wave w covers K/V rows (w*2+i)*8 + r8, i in {0,1}
        auto stage = [&](int k0, int buf) {
            #pragma unroll
            for (int i = 0; i < 2; ++i) {
                int row = (w * 2 + i) * 8 + r8;
                gll16(kbase + (size_t)(k0 + row) * D_MODEL + xcol, &Ks[buf][(w * 2 + i) * 512]);
                gll16(vbase + (size_t)row * SEQ + k0 + xcol,       &Vs[buf][(w * 2 + i) * 512]);
            }
        };

        stage(0, 0);

        // Q fragments (B-operand)
        bf16x8 Qf0, Qf1;
        {
            const unsigned short* qp = Q + hb + (size_t)qrow * D_MODEL + quad * 8;
            Qf0 = *(const bf16x8*)qp;
            Qf1 = *(const bf16x8*)(qp + 32);
        }

        f32x4 Oacc[4];
        #pragma unroll
        for (int nt = 0; nt < 4; ++nt) Oacc[nt] = (f32x4){0.f, 0.f, 0.f, 0.f};
        float m_run  = -INFINITY;
        float l_lane = 0.f;                  // per-lane partial; reduced in epilogue

        __syncthreads();                     // drains vmcnt -> tile 0 staged

        int bb = 0;
        for (int kt = 0; kt <= qt; ++kt) {
            const int k0 = kt * 64;
            const unsigned short* Kc = Ks[bb];
            const unsigned short* Vc = Vs[bb];
            if (kt < qt) stage(k0 + 64, bb ^ 1);   // async, drained at iter-end barrier

            // ---- S^T = K Q^T (lane owns q-row lm; kv = ct*16+quad*4+r) ----
            f32x4 S[4];
            __builtin_amdgcn_s_setprio(1);
            #pragma unroll
            for (int ct = 0; ct < 4; ++ct) {
                bf16x8 a0 = *(const bf16x8*)&Kc[(ct * 16 + lm) * 64 + ((quad ^ (lm & 7)) * 8)];
                bf16x8 a1 = *(const bf16x8*)&Kc[(ct * 16 + lm) * 64 + (((4 + quad) ^ (lm & 7)) * 8)];
                f32x4 z = (f32x4){0.f, 0.f, 0.f, 0.f};
                z = __builtin_amdgcn_mfma_f32_16x16x32_bf16(a0, Qf0, z, 0, 0, 0);
                z = __builtin_amdgcn_mfma_f32_16x16x32_bf16(a1, Qf1, z, 0, 0, 0);
                S[ct] = z;
            }
            __builtin_amdgcn_s_setprio(0);

            // causal mask (diag-straddling tiles only)
            if (k0 + 63 > q0 + w * 16) {
                #pragma unroll
                for (int ct = 0; ct < 4; ++ct)
                    #pragma unroll
                    for (int r = 0; r < 4; ++r)
                        if ((k0 + ct * 16 + quad * 4 + r) > qrow)
                            S[ct][r] = -1e30f;
            }

            // ---- lane-local online softmax, exp2 domain ----
            float ml = fmaxf(fmaxf(fmaxf(S[0][0], S[0][1]), fmaxf(S[0][2], S[0][3])),
                             fmaxf(fmaxf(S[1][0], S[1][1]), fmaxf(S[1][2], S[1][3])));
            ml = fmaxf(ml, fmaxf(fmaxf(fmaxf(S[2][0], S[2][1]), fmaxf(S[2][2], S[2][3])),
                                 fmaxf(fmaxf(S[3][0], S[3][1]), fmaxf(S[3][2], S[3][3]))));
            // defer-rescale: cross-lane reduce + O rescale only when a lane's
            // max outgrew the bound (P stays <= 2^8 in f32 accum otherwise).
            if (__any(ml > m_run + 8.0f)) {
                float m = fmaxf(ml, __shfl_xor(ml, 16));
                m = fmaxf(m, __shfl_xor(m, 32));
                const float m_new = fmaxf(m_run, m);
                const float alpha = exp2_fast(m_run - m_new);
                #pragma unroll
                for (int nt = 0; nt < 4; ++nt)
                    #pragma unroll
                    for (int r = 0; r < 4; ++r) Oacc[nt][r] *= alpha;
                l_lane *= alpha;
                m_run = m_new;
            }
            float psum = 0.f;
            #pragma unroll
            for (int ct = 0; ct < 4; ++ct)
                #pragma unroll
                for (int r = 0; r < 4; ++r) {
                    float e = exp2_fast(S[ct][r] - m_run);
                    S[ct][r] = e;
                    psum += e;
                }
            l_lane += psum;                  // per-lane; no shuffle

            // ---- P^T -> wave-private slab (swizzled, v_perm truncation pack) ----
            #pragma unroll
            for (int ct = 0; ct < 4; ++ct) {
                uint2 pw = make_uint2(pack_hi(S[ct][0], S[ct][1]),
                                      pack_hi(S[ct][2], S[ct][3]));
                int lc = 2 * ct + (quad >> 1);
                *(uint2*)&ps[lm * 64 + ((lc ^ (lm & 7)) * 8) + (quad & 1) * 4] = pw;
            }
            bf16x8 Pb0 = *(const bf16x8*)&ps[lm * 64 + ((quad ^ (lm & 7)) * 8)];
            bf16x8 Pb1 = *(const bf16x8*)&ps[lm * 64 + (((4 + quad) ^ (lm & 7)) * 8)];

            // ---- O^T += V^T P^T ----
            __builtin_amdgcn_s_setprio(1);
            #pragma unroll
            for (int nt = 0; nt < 4; ++nt) {
                bf16x8 a0 = *(const bf16x8*)&Vc[(nt * 16 + lm) * 64 + ((quad ^ (lm & 7)) * 8)];
                bf16x8 a1 = *(const bf16x8*)&Vc[(nt * 16 + lm) * 64 + (((4 + quad) ^ (lm & 7)) * 8)];
                f32x4 o = Oacc[nt];
                o = __builtin_amdgcn_mfma_f32_16x16x32_bf16(a0, Pb0, o, 0, 0, 0);
                o = __builtin_amdgcn_mfma_f32_16x16x32_bf16(a1, Pb1, o, 0, 0, 0);
                Oacc[nt] = o;
            }
            __builtin_amdgcn_s_setprio(0);

            __syncthreads();                 // buf swap: drains gll16 (vmcnt) + ds
            bb ^= 1;
        }

        // ---- epilogue: reduce l across quad-group (once), normalize, store ----
        float l = l_lane + __shfl_xor(l_lane, 16);
        l += __shfl_xor(l, 32);
        const float inv_l = 1.f / l;
        #pragma unroll
        for (int nt = 0; nt < 4; ++nt) {
            ushort4 pk = make_ushort4(f2bf(Oacc[nt][0] * inv_l), f2bf(Oacc[nt][1] * inv_l),
                                      f2bf(Oacc[nt][2] * inv_l), f2bf(Oacc[nt][3] * inv_l));
            int lc = 2 * nt + (quad >> 1);
            *(ushort4*)&ps[lm * 64 + ((lc ^ (lm & 7)) * 8) + (quad & 1) * 4] = pk;
        }
        #pragma unroll
        for (int p = 0; p < 2; ++p) {
            int qr = p * 8 + r8;
            int dc = sl * 8;
            uint4 val = *(const uint4*)&ps[qr * 64 + ((sl ^ (qr & 7)) * 8)];
            *(uint4*)&A[hb + (size_t)(q0 + w * 16 + qr) * D_MODEL + dc] = val;
        }

        // ---- pop next item (t0 is wave 0: its epilogue LDS reads precede
        //      this write in program order; other waves use their own slabs) ----
        if (t == 0) *item_slot = (int)atomicAdd(&g_attn_cnt, 1u);
        __syncthreads();
        item = *item_slot;
    }
}

// ---------------------------------------------------------------------------
extern "C" void kernel_launch(void* const* d_in, const int* in_sizes, int n_in,
                              void* d_out, int out_size, void* d_ws, size_t ws_size,
                              hipStream_t stream) {
    const float* q  = (const float*)d_in[0];
    const float* k  = (const float*)d_in[1];
    const float* v  = (const float*)d_in[2];
    const float* Wq = (const float*)d_in[4];
    const float* Wk = (const float*)d_in[5];
    const float* Wv = (const float*)d_in[6];
    const float* Wo = (const float*)d_in[7];
    float* out = (float*)d_out;

    char* ws = (char*)d_ws;
    const size_t MB = 1024 * 1024;
    unsigned short* qb  = (unsigned short*)(ws + 0 * MB);
    unsigned short* kb  = (unsigned short*)(ws + 8 * MB);
    unsigned short* vb  = (unsigned short*)(ws + 16 * MB);
    unsigned short* wqb = (unsigned short*)(ws + 24 * MB);
    unsigned short* wkb = (unsigned short*)(ws + 26 * MB);
    unsigned short* wvb = (unsigned short*)(ws + 28 * MB);
    unsigned short* wob = (unsigned short*)(ws + 30 * MB);
    unsigned short* Qp  = (unsigned short*)(ws + 32 * MB);
    unsigned short* Kp  = (unsigned short*)(ws + 40 * MB);
    unsigned short* VTp = (unsigned short*)(ws + 48 * MB);
    unsigned short* Ap  = (unsigned short*)(ws + 56 * MB);

    const int nX8 = BS * D_MODEL / 8;
    const int nW8 = D_MODEL * D_MODEL / 8;
    cast_act<<<dim3(nX8 / 256, 3), 256, 0, stream>>>(q, k, v, qb, kb, vb, nX8);
    cast_wt <<<dim3(nW8 / 256, 4), 256, 0, stream>>>(Wq, Wk, Wv, Wo, wqb, wkb, wvb, wob, nW8);

    proj_gemm<<<dim3(D_MODEL / 128, BS / 128, 3), 256, 0, stream>>>(
        qb, kb, vb, wqb, wkb, wvb, Qp, Kp, VTp);

    attn_mfma<<<dim3(1024), 256, 0, stream>>>(Qp, Kp, VTp, Ap);

    out_gemm<<<dim3(D_MODEL / 64, BS / 128), 256, 0, stream>>>(Ap, wob, out);
}

// Round 4
// 218.792 us; speedup vs baseline: 1.1326x; 1.1326x over previous
//
#include <hip/hip_runtime.h>
#include <hip/hip_bf16.h>

#define D_MODEL 1024
#define NHEAD   16
#define HDK     64
#define SEQ     2048
#define BATCH   2
#define BS      (BATCH * SEQ)

typedef __attribute__((ext_vector_type(8))) short bf16x8;
typedef __attribute__((ext_vector_type(4))) float f32x4;
typedef __attribute__((ext_vector_type(4))) unsigned int u32x4;

__device__ __forceinline__ unsigned short f2bf(float f) {
    unsigned u = __builtin_bit_cast(unsigned, f);
    u += 0x7fffu + ((u >> 16) & 1u);          // round-to-nearest-even
    return (unsigned short)(u >> 16);
}

// pack hi16(x):hi16(y) -> (hi16(y)<<16)|hi16(x) with one v_perm_b32 (truncation)
__device__ __forceinline__ unsigned pack_hi(float x, float y) {
    return __builtin_amdgcn_perm(__builtin_bit_cast(unsigned, y),
                                 __builtin_bit_cast(unsigned, x), 0x07060302u);
}

// guaranteed-native 2^x (exp2f() can lower to a slow libcall)
__device__ __forceinline__ float exp2_fast(float x) {
    float r;
    asm("v_exp_f32 %0, %1" : "=v"(r) : "v"(x));
    return r;
}

typedef const void __attribute__((address_space(1))) gas_void;
typedef void __attribute__((address_space(3))) las_void;

__device__ __forceinline__ void gll16(const void* g, void* l) {
    __builtin_amdgcn_global_load_lds((gas_void*)g, (las_void*)l, 16, 0, 0);
}

// ---------------------------------------------------------------------------
// fp32 -> bf16 casts
// ---------------------------------------------------------------------------
__device__ __forceinline__ void cast_body(const float* __restrict__ src,
                                          unsigned short* __restrict__ dst, int i) {
    const float4* p = (const float4*)src + (size_t)i * 2;
    float4 a = p[0], b = p[1];
    ushort4 lo = make_ushort4(f2bf(a.x), f2bf(a.y), f2bf(a.z), f2bf(a.w));
    ushort4 hi = make_ushort4(f2bf(b.x), f2bf(b.y), f2bf(b.z), f2bf(b.w));
    ushort4* q = (ushort4*)dst + (size_t)i * 2;
    q[0] = lo; q[1] = hi;
}

__global__ __launch_bounds__(256)
void cast_act(const float* a, const float* b, const float* c,
              unsigned short* oa, unsigned short* ob, unsigned short* oc, int n8) {
    int i = blockIdx.x * 256 + threadIdx.x;
    if (i >= n8) return;
    const float* s = blockIdx.y == 0 ? a : blockIdx.y == 1 ? b : c;
    unsigned short* d = blockIdx.y == 0 ? oa : blockIdx.y == 1 ? ob : oc;
    cast_body(s, d, i);
}

__global__ __launch_bounds__(256)
void cast_wt(const float* a, const float* b, const float* c, const float* dd,
             unsigned short* oa, unsigned short* ob, unsigned short* oc, unsigned short* od, int n8) {
    int i = blockIdx.x * 256 + threadIdx.x;
    if (i >= n8) return;
    const float* s = blockIdx.y == 0 ? a : blockIdx.y == 1 ? b : blockIdx.y == 2 ? c : dd;
    unsigned short* d = blockIdx.y == 0 ? oa : blockIdx.y == 1 ? ob : blockIdx.y == 2 ? oc : od;
    cast_body(s, d, i);
}

// ---------------------------------------------------------------------------
// GEMM K-loop, BM=128 BN=128 BK=64, 256 thr, wave -> 64x64 quadrant.
// ---------------------------------------------------------------------------
__device__ __forceinline__ void gemm_kloop128(const unsigned short* __restrict__ X,
                                              const unsigned short* __restrict__ W,
                                              unsigned short* As, unsigned short* Bs,
                                              int bm, int bn, f32x4 acc[4][4]) {
    const int t    = threadIdx.x;
    const int w    = t >> 6;
    const int L    = t & 63;
    const int quad = L >> 4;
    const int lm   = L & 15;
    const int r8   = L >> 3;
    const int sl   = L & 7;
    const int xcol = ((sl ^ r8) & 7) * 8;
    const int wr   = (w >> 1) * 64;
    const int wc   = (w & 1) * 64;

    for (int kt = 0; kt < D_MODEL; kt += 64) {
        __syncthreads();
        #pragma unroll
        for (int i = 0; i < 4; ++i) {
            int c = w * 4 + i;
            gll16(X + (size_t)(bm + c * 8 + r8) * D_MODEL + kt + xcol, &As[c * 512]);
        }
        #pragma unroll
        for (int i = 0; i < 4; ++i) {
            int c = w * 4 + i;
            gll16(W + (size_t)(bn + c * 8 + r8) * D_MODEL + kt + xcol, &Bs[c * 512]);
        }
        __syncthreads();

        #pragma unroll
        for (int ch = 0; ch < 2; ++ch) {
            bf16x8 af[4], bfr[4];
            #pragma unroll
            for (int ms = 0; ms < 4; ++ms) {
                int row = wr + ms * 16 + lm;
                af[ms] = *(const bf16x8*)&As[row * 64 + (((ch * 4 + quad) ^ (row & 7)) * 8)];
            }
            #pragma unroll
            for (int ns = 0; ns < 4; ++ns) {
                int row = wc + ns * 16 + lm;
                bfr[ns] = *(const bf16x8*)&Bs[row * 64 + (((ch * 4 + quad) ^ (row & 7)) * 8)];
            }
            #pragma unroll
            for (int ms = 0; ms < 4; ++ms)
                #pragma unroll
                for (int ns = 0; ns < 4; ++ns)
                    acc[ms][ns] = __builtin_amdgcn_mfma_f32_16x16x32_bf16(
                        af[ms], bfr[ns], acc[ms][ns], 0, 0, 0);
        }
    }
}

// BM=128 BN=64 variant (more blocks for the small out_gemm)
__device__ __forceinline__ void gemm_kloop64(const unsigned short* __restrict__ X,
                                             const unsigned short* __restrict__ W,
                                             unsigned short* As, unsigned short* Bs,
                                             int bm, int bn, f32x4 acc[2][4]) {
    const int t    = threadIdx.x;
    const int w    = t >> 6;
    const int L    = t & 63;
    const int quad = L >> 4;
    const int lm   = L & 15;
    const int r8   = L >> 3;
    const int sl   = L & 7;
    const int xcol = ((sl ^ r8) & 7) * 8;

    for (int kt = 0; kt < D_MODEL; kt += 64) {
        __syncthreads();
        #pragma unroll
        for (int i = 0; i < 4; ++i) {
            int c = w * 4 + i;
            gll16(X + (size_t)(bm + c * 8 + r8) * D_MODEL + kt + xcol, &As[c * 512]);
        }
        #pragma unroll
        for (int i = 0; i < 2; ++i) {
            int c = w * 2 + i;
            gll16(W + (size_t)(bn + c * 8 + r8) * D_MODEL + kt + xcol, &Bs[c * 512]);
        }
        __syncthreads();

        #pragma unroll
        for (int ch = 0; ch < 2; ++ch) {
            bf16x8 af[2], bfr[4];
            #pragma unroll
            for (int ms = 0; ms < 2; ++ms) {
                int row = w * 32 + ms * 16 + lm;
                af[ms] = *(const bf16x8*)&As[row * 64 + (((ch * 4 + quad) ^ (row & 7)) * 8)];
            }
            #pragma unroll
            for (int ns = 0; ns < 4; ++ns) {
                int row = ns * 16 + lm;
                bfr[ns] = *(const bf16x8*)&Bs[row * 64 + (((ch * 4 + quad) ^ (row & 7)) * 8)];
            }
            #pragma unroll
            for (int ms = 0; ms < 2; ++ms)
                #pragma unroll
                for (int ns = 0; ns < 4; ++ns)
                    acc[ms][ns] = __builtin_amdgcn_mfma_f32_16x16x32_bf16(
                        af[ms], bfr[ns], acc[ms][ns], 0, 0, 0);
        }
    }
}

// ---------------------------------------------------------------------------
// Fused Q/K/V projections. z=0: Q (x 0.125*log2(e) -> exp2-domain softmax,
// row-major), z=1: K (row-major), z=2: V transposed per head.
// ---------------------------------------------------------------------------
__global__ __launch_bounds__(256, 3)
void proj_gemm(const unsigned short* __restrict__ qx, const unsigned short* __restrict__ kx,
               const unsigned short* __restrict__ vx, const unsigned short* __restrict__ wq,
               const unsigned short* __restrict__ wk, const unsigned short* __restrict__ wv,
               unsigned short* __restrict__ Qp, unsigned short* __restrict__ Kp,
               unsigned short* __restrict__ VT) {
    __shared__ __align__(16) unsigned short As[128 * 64];
    __shared__ __align__(16) unsigned short Bs[128 * 64];

    const int p = blockIdx.z;
    const unsigned short* X = p == 0 ? qx : p == 1 ? kx : vx;
    const unsigned short* W = p == 0 ? wq : p == 1 ? wk : wv;
    const int bm = blockIdx.y * 128, bn = blockIdx.x * 128;

    f32x4 acc[4][4];
    #pragma unroll
    for (int ms = 0; ms < 4; ++ms)
        #pragma unroll
        for (int ns = 0; ns < 4; ++ns)
            acc[ms][ns] = (f32x4){0.f, 0.f, 0.f, 0.f};

    gemm_kloop128(X, W, As, Bs, bm, bn, acc);

    const int t = threadIdx.x, w = t >> 6, L = t & 63, quad = L >> 4, lm = L & 15;
    const int wr = (w >> 1) * 64, wc = (w & 1) * 64;
    if (p == 2) {
        const int b    = bm >> 11;
        const int s_in = (bm & (SEQ - 1)) + wr;
        #pragma unroll
        for (int ms = 0; ms < 4; ++ms)
            #pragma unroll
            for (int ns = 0; ns < 4; ++ns) {
                int dg = bn + wc + ns * 16 + lm;
                int h  = dg >> 6, d = dg & 63;
                ushort4 pk = make_ushort4(f2bf(acc[ms][ns][0]), f2bf(acc[ms][ns][1]),
                                          f2bf(acc[ms][ns][2]), f2bf(acc[ms][ns][3]));
                *(ushort4*)&VT[((size_t)((b * NHEAD + h) * HDK + d)) * SEQ +
                               s_in + ms * 16 + quad * 4] = pk;
            }
    } else {
        unsigned short* Y = p == 0 ? Qp : Kp;
        // 0.125 * log2(e): softmax runs in exp2 domain (saves a v_mul per exp)
        const float scl = p == 0 ? 0.18033688011112042f : 1.0f;
        #pragma unroll
        for (int ms = 0; ms < 4; ++ms)
            #pragma unroll
            for (int ns = 0; ns < 4; ++ns)
                #pragma unroll
                for (int r = 0; r < 4; ++r)
                    Y[(size_t)(bm + wr + ms * 16 + quad * 4 + r) * D_MODEL +
                      bn + wc + ns * 16 + lm] = f2bf(acc[ms][ns][r] * scl);
    }
}

__global__ __launch_bounds__(256)
void out_gemm(const unsigned short* __restrict__ X, const unsigned short* __restrict__ W,
              float* __restrict__ Y) {
    __shared__ __align__(16) unsigned short As[128 * 64];
    __shared__ __align__(16) unsigned short Bs[64 * 64];
    const int bm = blockIdx.y * 128, bn = blockIdx.x * 64;

    f32x4 acc[2][4];
    #pragma unroll
    for (int ms = 0; ms < 2; ++ms)
        #pragma unroll
        for (int ns = 0; ns < 4; ++ns)
            acc[ms][ns] = (f32x4){0.f, 0.f, 0.f, 0.f};

    gemm_kloop64(X, W, As, Bs, bm, bn, acc);

    const int t = threadIdx.x, w = t >> 6, L = t & 63, quad = L >> 4, lm = L & 15;
    #pragma unroll
    for (int ms = 0; ms < 2; ++ms)
        #pragma unroll
        for (int ns = 0; ns < 4; ++ns)
            #pragma unroll
            for (int r = 0; r < 4; ++r)
                Y[(size_t)(bm + w * 32 + ms * 16 + quad * 4 + r) * D_MODEL +
                  bn + ns * 16 + lm] = acc[ms][ns][r];
}

// ---------------------------------------------------------------------------
// Flash attention, causal, S^T formulation.
// Round-4:
//  - FIXED item decode (round 3 generated 2048 items = 2x duplicate work +
//    OOB batch indices; correct count is 32 bh x 32 qt = 1024).
//  - sum-balanced static quartet schedule: under the evidenced period-256
//    round-robin block->CU mapping, CU-period u runs items {u,u+256,u+512,
//    u+768} with qt = {qb, 31-qb, (qb+16)&31, (15-qb)&31} -> every CU gets
//    exactly 66 tiles; long chains start at t=0.
//  - P^T -> B-fragment via v_permlane32_swap + v_permlane16_swap (no LDS
//    round trip): owners quads {(2q)&3,(2q+1)&3} at same lm; swap32 then
//    swap16 produce P_lo/P_hi exactly. Frees the 8 KB Ps slab -> LDS 32768 B;
//    epilogue reuses the then-dead Ks[0] as its transpose slab.
// ---------------------------------------------------------------------------
__global__ __launch_bounds__(256, 4)
void attn_mfma(const unsigned short* __restrict__ Q, const unsigned short* __restrict__ K,
               const unsigned short* __restrict__ VT, unsigned short* __restrict__ A) {
    __shared__ __align__(16) unsigned short Ks[2][64 * 64];   // [buf][kv][d]  (xor-swizzled)
    __shared__ __align__(16) unsigned short Vs[2][64 * 64];   // [buf][d][kv]  (xor-swizzled)

    const int t    = threadIdx.x;
    const int w    = t >> 6;
    const int L    = t & 63;
    const int quad = L >> 4;
    const int lm   = L & 15;
    const int r8   = L >> 3;
    const int sl   = L & 7;
    const int xcol = (sl ^ r8) * 8;          // pre-swizzled global column for gll16

    // balanced quartet decode (see header)
    const int id  = blockIdx.x;
    const int u   = id & 255;
    const int p   = id >> 8;                 // 0..3
    const int qb_ = u >> 3;                  // 0..31
    const int qt  = p == 0 ? qb_
                  : p == 1 ? 31 - qb_
                  : p == 2 ? (qb_ + 16) & 31
                           : (15 - qb_) & 31;
    const int bh  = (u & 7) | (p << 3);      // 0..31
    const int h   = bh & 15;
    const int b   = bh >> 4;

    const size_t hb   = (size_t)b * SEQ * D_MODEL + h * HDK;
    const size_t vrow = (size_t)(b * NHEAD + h) * HDK * SEQ;

    const unsigned short* kbase = K + hb;
    const unsigned short* vbase = VT + vrow;

    const int q0   = qt * 64;
    const int qrow = q0 + w * 16 + lm;

    // staging: wave w covers K/V rows (w*2+i)*8 + r8, i in {0,1}
    auto stage = [&](int k0, int buf) {
        #pragma unroll
        for (int i = 0; i < 2; ++i) {
            int row = (w * 2 + i) * 8 + r8;
            gll16(kbase + (size_t)(k0 + row) * D_MODEL + xcol, &Ks[buf][(w * 2 + i) * 512]);
            gll16(vbase + (size_t)row * SEQ + k0 + xcol,       &Vs[buf][(w * 2 + i) * 512]);
        }
    };

    stage(0, 0);

    // Q fragments (B-operand)
    bf16x8 Qf0, Qf1;
    {
        const unsigned short* qp = Q + hb + (size_t)qrow * D_MODEL + quad * 8;
        Qf0 = *(const bf16x8*)qp;
        Qf1 = *(const bf16x8*)(qp + 32);
    }

    f32x4 Oacc[4];
    #pragma unroll
    for (int nt = 0; nt < 4; ++nt) Oacc[nt] = (f32x4){0.f, 0.f, 0.f, 0.f};
    float m_run  = -INFINITY;
    float l_lane = 0.f;                      // per-lane partial; reduced in epilogue

    __syncthreads();                         // drains vmcnt -> tile 0 staged

    int bb = 0;
    for (int kt = 0; kt <= qt; ++kt) {
        const int k0 = kt * 64;
        const unsigned short* Kc = Ks[bb];
        const unsigned short* Vc = Vs[bb];
        if (kt < qt) stage(k0 + 64, bb ^ 1);   // async, drained at iter-end barrier

        // ---- S^T = K Q^T (lane owns q-row lm; kv = ct*16+quad*4+r) ----
        f32x4 S[4];
        __builtin_amdgcn_s_setprio(1);
        #pragma unroll
        for (int ct = 0; ct < 4; ++ct) {
            bf16x8 a0 = *(const bf16x8*)&Kc[(ct * 16 + lm) * 64 + ((quad ^ (lm & 7)) * 8)];
            bf16x8 a1 = *(const bf16x8*)&Kc[(ct * 16 + lm) * 64 + (((4 + quad) ^ (lm & 7)) * 8)];
            f32x4 z = (f32x4){0.f, 0.f, 0.f, 0.f};
            z = __builtin_amdgcn_mfma_f32_16x16x32_bf16(a0, Qf0, z, 0, 0, 0);
            z = __builtin_amdgcn_mfma_f32_16x16x32_bf16(a1, Qf1, z, 0, 0, 0);
            S[ct] = z;
        }
        __builtin_amdgcn_s_setprio(0);

        // causal mask (diag-straddling tiles only)
        if (k0 + 63 > q0 + w * 16) {
            #pragma unroll
            for (int ct = 0; ct < 4; ++ct)
                #pragma unroll
                for (int r = 0; r < 4; ++r)
                    if ((k0 + ct * 16 + quad * 4 + r) > qrow)
                        S[ct][r] = -1e30f;
        }

        // ---- lane-local online softmax, exp2 domain ----
        float ml = fmaxf(fmaxf(fmaxf(S[0][0], S[0][1]), fmaxf(S[0][2], S[0][3])),
                         fmaxf(fmaxf(S[1][0], S[1][1]), fmaxf(S[1][2], S[1][3])));
        ml = fmaxf(ml, fmaxf(fmaxf(fmaxf(S[2][0], S[2][1]), fmaxf(S[2][2], S[2][3])),
                             fmaxf(fmaxf(S[3][0], S[3][1]), fmaxf(S[3][2], S[3][3]))));
        // defer-rescale: cross-lane reduce + O rescale only when a lane's
        // max outgrew the bound (P stays <= 2^8 in f32 accum otherwise).
        if (__any(ml > m_run + 8.0f)) {
            float m = fmaxf(ml, __shfl_xor(ml, 16));
            m = fmaxf(m, __shfl_xor(m, 32));
            const float m_new = fmaxf(m_run, m);
            const float alpha = exp2_fast(m_run - m_new);
            #pragma unroll
            for (int nt = 0; nt < 4; ++nt)
                #pragma unroll
                for (int r = 0; r < 4; ++r) Oacc[nt][r] *= alpha;
            l_lane *= alpha;
            m_run = m_new;
        }
        float psum = 0.f;
        #pragma unroll
        for (int ct = 0; ct < 4; ++ct)
            #pragma unroll
            for (int r = 0; r < 4; ++r) {
                float e = exp2_fast(S[ct][r] - m_run);
                S[ct][r] = e;
                psum += e;
            }
        l_lane += psum;                      // per-lane; no shuffle

        // ---- P^T -> B-fragments via permlane swaps (no LDS round-trip) ----
        // swap32(x,y): x'={x.lo,y.lo}, y'={x.hi,y.hi}
        // swap16(a,b): a'={a.q0,b.q0,a.q2,b.q2}, b'={a.q1,b.q1,a.q3,b.q3}
        // -> x: P_lo (kv quad*8+{0..3}), y: P_hi (kv quad*8+{4..7})
        unsigned x0 = pack_hi(S[0][0], S[0][1]);
        unsigned x1 = pack_hi(S[0][2], S[0][3]);
        unsigned y0 = pack_hi(S[1][0], S[1][1]);
        unsigned y1 = pack_hi(S[1][2], S[1][3]);
        asm("v_permlane32_swap_b32 %0, %1" : "+v"(x0), "+v"(y0));
        asm("v_permlane32_swap_b32 %0, %1" : "+v"(x1), "+v"(y1));
        asm("v_permlane16_swap_b32 %0, %1" : "+v"(x0), "+v"(y0));
        asm("v_permlane16_swap_b32 %0, %1" : "+v"(x1), "+v"(y1));
        bf16x8 Pb0 = __builtin_bit_cast(bf16x8, (u32x4){x0, x1, y0, y1});
        unsigned x2 = pack_hi(S[2][0], S[2][1]);
        unsigned x3 = pack_hi(S[2][2], S[2][3]);
        unsigned y2 = pack_hi(S[3][0], S[3][1]);
        unsigned y3 = pack_hi(S[3][2], S[3][3]);
        asm("v_permlane32_swap_b32 %0, %1" : "+v"(x2), "+v"(y2));
        asm("v_permlane32_swap_b32 %0, %1" : "+v"(x3), "+v"(y3));
        asm("v_permlane16_swap_b32 %0, %1" : "+v"(x2), "+v"(y2));
        asm("v_permlane16_swap_b32 %0, %1" : "+v"(x3), "+v"(y3));
        bf16x8 Pb1 = __builtin_bit_cast(bf16x8, (u32x4){x2, x3, y2, y3});

        // ---- O^T += V^T P^T ----
        __builtin_amdgcn_s_setprio(1);
        #pragma unroll
        for (int nt = 0; nt < 4; ++nt) {
            bf16x8 a0 = *(const bf16x8*)&Vc[(nt * 16 + lm) * 64 + ((quad ^ (lm & 7)) * 8)];
            bf16x8 a1 = *(const bf16x8*)&Vc[(nt * 16 + lm) * 64 + (((4 + quad) ^ (lm & 7)) * 8)];
            f32x4 o = Oacc[nt];
            o = __builtin_amdgcn_mfma_f32_16x16x32_bf16(a0, Pb0, o, 0, 0, 0);
            o = __builtin_amdgcn_mfma_f32_16x16x32_bf16(a1, Pb1, o, 0, 0, 0);
            Oacc[nt] = o;
        }
        __builtin_amdgcn_s_setprio(0);

        __syncthreads();                     // buf swap: drains gll16 (vmcnt) + ds
        bb ^= 1;
    }

    // ---- epilogue: reduce l across quad-group (once), normalize, store.
    //      Ks[0] is dead after the loop-end barrier -> per-wave 16x64 slab. ----
    float l = l_lane + __shfl_xor(l_lane, 16);
    l += __shfl_xor(l, 32);
    const float inv_l = 1.f / l;
    unsigned short* es = &Ks[0][w * 1024];
    #pragma unroll
    for (int nt = 0; nt < 4; ++nt) {
        ushort4 pk = make_ushort4(f2bf(Oacc[nt][0] * inv_l), f2bf(Oacc[nt][1] * inv_l),
                                  f2bf(Oacc[nt][2] * inv_l), f2bf(Oacc[nt][3] * inv_l));
        int lc = 2 * nt + (quad >> 1);
        *(ushort4*)&es[lm * 64 + ((lc ^ (lm & 7)) * 8) + (quad & 1) * 4] = pk;
    }
    #pragma unroll
    for (int pp = 0; pp < 2; ++pp) {
        int qr = pp * 8 + r8;
        int dc = sl * 8;
        uint4 val = *(const uint4*)&es[qr * 64 + ((sl ^ (qr & 7)) * 8)];
        *(uint4*)&A[hb + (size_t)(q0 + w * 16 + qr) * D_MODEL + dc] = val;
    }
}

// ---------------------------------------------------------------------------
extern "C" void kernel_launch(void* const* d_in, const int* in_sizes, int n_in,
                              void* d_out, int out_size, void* d_ws, size_t ws_size,
                              hipStream_t stream) {
    const float* q  = (const float*)d_in[0];
    const float* k  = (const float*)d_in[1];
    const float* v  = (const float*)d_in[2];
    const float* Wq = (const float*)d_in[4];
    const float* Wk = (const float*)d_in[5];
    const float* Wv = (const float*)d_in[6];
    const float* Wo = (const float*)d_in[7];
    float* out = (float*)d_out;

    char* ws = (char*)d_ws;
    const size_t MB = 1024 * 1024;
    unsigned short* qb  = (unsigned short*)(ws + 0 * MB);
    unsigned short* kb  = (unsigned short*)(ws + 8 * MB);
    unsigned short* vb  = (unsigned short*)(ws + 16 * MB);
    unsigned short* wqb = (unsigned short*)(ws + 24 * MB);
    unsigned short* wkb = (unsigned short*)(ws + 26 * MB);
    unsigned short* wvb = (unsigned short*)(ws + 28 * MB);
    unsigned short* wob = (unsigned short*)(ws + 30 * MB);
    unsigned short* Qp  = (unsigned short*)(ws + 32 * MB);
    unsigned short* Kp  = (unsigned short*)(ws + 40 * MB);
    unsigned short* VTp = (unsigned short*)(ws + 48 * MB);
    unsigned short* Ap  = (unsigned short*)(ws + 56 * MB);

    const int nX8 = BS * D_MODEL / 8;
    const int nW8 = D_MODEL * D_MODEL / 8;
    cast_act<<<dim3(nX8 / 256, 3), 256, 0, stream>>>(q, k, v, qb, kb, vb, nX8);
    cast_wt <<<dim3(nW8 / 256, 4), 256, 0, stream>>>(Wq, Wk, Wv, Wo, wqb, wkb, wvb, wob, nW8);

    proj_gemm<<<dim3(D_MODEL / 128, BS / 128, 3), 256, 0, stream>>>(
        qb, kb, vb, wqb, wkb, wvb, Qp, Kp, VTp);

    attn_mfma<<<dim3(1024), 256, 0, stream>>>(Qp, Kp, VTp, Ap);

    out_gemm<<<dim3(D_MODEL / 64, BS / 128), 256, 0, stream>>>(Ap, wob, out);
}

// Round 5
// 216.932 us; speedup vs baseline: 1.1423x; 1.0086x over previous
//
#include <hip/hip_runtime.h>
#include <hip/hip_bf16.h>

#define D_MODEL 1024
#define NHEAD   16
#define HDK     64
#define SEQ     2048
#define BATCH   2
#define BS      (BATCH * SEQ)

typedef __attribute__((ext_vector_type(8))) short bf16x8;
typedef __attribute__((ext_vector_type(4))) float f32x4;
typedef __attribute__((ext_vector_type(4))) unsigned int u32x4;

__device__ __forceinline__ unsigned short f2bf(float f) {
    unsigned u = __builtin_bit_cast(unsigned, f);
    u += 0x7fffu + ((u >> 16) & 1u);          // round-to-nearest-even
    return (unsigned short)(u >> 16);
}

// pack hi16(x):hi16(y) -> (hi16(y)<<16)|hi16(x) with one v_perm_b32 (truncation)
__device__ __forceinline__ unsigned pack_hi(float x, float y) {
    return __builtin_amdgcn_perm(__builtin_bit_cast(unsigned, y),
                                 __builtin_bit_cast(unsigned, x), 0x07060302u);
}

// guaranteed-native 2^x (exp2f() can lower to a slow libcall)
__device__ __forceinline__ float exp2_fast(float x) {
    float r;
    asm("v_exp_f32 %0, %1" : "=v"(r) : "v"(x));
    return r;
}

// 3-input max; clang fuses nested fmaxf to v_max3_f32
__device__ __forceinline__ float max3(float a, float b, float c) {
    return fmaxf(fmaxf(a, b), c);
}

typedef const void __attribute__((address_space(1))) gas_void;
typedef void __attribute__((address_space(3))) las_void;

__device__ __forceinline__ void gll16(const void* g, void* l) {
    __builtin_amdgcn_global_load_lds((gas_void*)g, (las_void*)l, 16, 0, 0);
}

// ---------------------------------------------------------------------------
// fp32 -> bf16 casts
// ---------------------------------------------------------------------------
__device__ __forceinline__ void cast_body(const float* __restrict__ src,
                                          unsigned short* __restrict__ dst, int i) {
    const float4* p = (const float4*)src + (size_t)i * 2;
    float4 a = p[0], b = p[1];
    ushort4 lo = make_ushort4(f2bf(a.x), f2bf(a.y), f2bf(a.z), f2bf(a.w));
    ushort4 hi = make_ushort4(f2bf(b.x), f2bf(b.y), f2bf(b.z), f2bf(b.w));
    ushort4* q = (ushort4*)dst + (size_t)i * 2;
    q[0] = lo; q[1] = hi;
}

__global__ __launch_bounds__(256)
void cast_act(const float* a, const float* b, const float* c,
              unsigned short* oa, unsigned short* ob, unsigned short* oc, int n8) {
    int i = blockIdx.x * 256 + threadIdx.x;
    if (i >= n8) return;
    const float* s = blockIdx.y == 0 ? a : blockIdx.y == 1 ? b : c;
    unsigned short* d = blockIdx.y == 0 ? oa : blockIdx.y == 1 ? ob : oc;
    cast_body(s, d, i);
}

__global__ __launch_bounds__(256)
void cast_wt(const float* a, const float* b, const float* c, const float* dd,
             unsigned short* oa, unsigned short* ob, unsigned short* oc, unsigned short* od, int n8) {
    int i = blockIdx.x * 256 + threadIdx.x;
    if (i >= n8) return;
    const float* s = blockIdx.y == 0 ? a : blockIdx.y == 1 ? b : blockIdx.y == 2 ? c : dd;
    unsigned short* d = blockIdx.y == 0 ? oa : blockIdx.y == 1 ? ob : blockIdx.y == 2 ? oc : od;
    cast_body(s, d, i);
}

// ---------------------------------------------------------------------------
// GEMM K-loop, BM=128 BN=128 BK=64, 256 thr, wave -> 64x64 quadrant.
// ---------------------------------------------------------------------------
__device__ __forceinline__ void gemm_kloop128(const unsigned short* __restrict__ X,
                                              const unsigned short* __restrict__ W,
                                              unsigned short* As, unsigned short* Bs,
                                              int bm, int bn, f32x4 acc[4][4]) {
    const int t    = threadIdx.x;
    const int w    = t >> 6;
    const int L    = t & 63;
    const int quad = L >> 4;
    const int lm   = L & 15;
    const int r8   = L >> 3;
    const int sl   = L & 7;
    const int xcol = ((sl ^ r8) & 7) * 8;
    const int wr   = (w >> 1) * 64;
    const int wc   = (w & 1) * 64;

    for (int kt = 0; kt < D_MODEL; kt += 64) {
        __syncthreads();
        #pragma unroll
        for (int i = 0; i < 4; ++i) {
            int c = w * 4 + i;
            gll16(X + (size_t)(bm + c * 8 + r8) * D_MODEL + kt + xcol, &As[c * 512]);
        }
        #pragma unroll
        for (int i = 0; i < 4; ++i) {
            int c = w * 4 + i;
            gll16(W + (size_t)(bn + c * 8 + r8) * D_MODEL + kt + xcol, &Bs[c * 512]);
        }
        __syncthreads();

        #pragma unroll
        for (int ch = 0; ch < 2; ++ch) {
            bf16x8 af[4], bfr[4];
            #pragma unroll
            for (int ms = 0; ms < 4; ++ms) {
                int row = wr + ms * 16 + lm;
                af[ms] = *(const bf16x8*)&As[row * 64 + (((ch * 4 + quad) ^ (row & 7)) * 8)];
            }
            #pragma unroll
            for (int ns = 0; ns < 4; ++ns) {
                int row = wc + ns * 16 + lm;
                bfr[ns] = *(const bf16x8*)&Bs[row * 64 + (((ch * 4 + quad) ^ (row & 7)) * 8)];
            }
            #pragma unroll
            for (int ms = 0; ms < 4; ++ms)
                #pragma unroll
                for (int ns = 0; ns < 4; ++ns)
                    acc[ms][ns] = __builtin_amdgcn_mfma_f32_16x16x32_bf16(
                        af[ms], bfr[ns], acc[ms][ns], 0, 0, 0);
        }
    }
}

// BM=128 BN=64 variant (more blocks for the small out_gemm)
__device__ __forceinline__ void gemm_kloop64(const unsigned short* __restrict__ X,
                                             const unsigned short* __restrict__ W,
                                             unsigned short* As, unsigned short* Bs,
                                             int bm, int bn, f32x4 acc[2][4]) {
    const int t    = threadIdx.x;
    const int w    = t >> 6;
    const int L    = t & 63;
    const int quad = L >> 4;
    const int lm   = L & 15;
    const int r8   = L >> 3;
    const int sl   = L & 7;
    const int xcol = ((sl ^ r8) & 7) * 8;

    for (int kt = 0; kt < D_MODEL; kt += 64) {
        __syncthreads();
        #pragma unroll
        for (int i = 0; i < 4; ++i) {
            int c = w * 4 + i;
            gll16(X + (size_t)(bm + c * 8 + r8) * D_MODEL + kt + xcol, &As[c * 512]);
        }
        #pragma unroll
        for (int i = 0; i < 2; ++i) {
            int c = w * 2 + i;
            gll16(W + (size_t)(bn + c * 8 + r8) * D_MODEL + kt + xcol, &Bs[c * 512]);
        }
        __syncthreads();

        #pragma unroll
        for (int ch = 0; ch < 2; ++ch) {
            bf16x8 af[2], bfr[4];
            #pragma unroll
            for (int ms = 0; ms < 2; ++ms) {
                int row = w * 32 + ms * 16 + lm;
                af[ms] = *(const bf16x8*)&As[row * 64 + (((ch * 4 + quad) ^ (row & 7)) * 8)];
            }
            #pragma unroll
            for (int ns = 0; ns < 4; ++ns) {
                int row = ns * 16 + lm;
                bfr[ns] = *(const bf16x8*)&Bs[row * 64 + (((ch * 4 + quad) ^ (row & 7)) * 8)];
            }
            #pragma unroll
            for (int ms = 0; ms < 2; ++ms)
                #pragma unroll
                for (int ns = 0; ns < 4; ++ns)
                    acc[ms][ns] = __builtin_amdgcn_mfma_f32_16x16x32_bf16(
                        af[ms], bfr[ns], acc[ms][ns], 0, 0, 0);
        }
    }
}

// ---------------------------------------------------------------------------
// Fused Q/K/V projections. z=0: Q (x 0.125*log2(e) -> exp2-domain softmax,
// row-major), z=1: K (row-major), z=2: V transposed per head.
// ---------------------------------------------------------------------------
__global__ __launch_bounds__(256, 3)
void proj_gemm(const unsigned short* __restrict__ qx, const unsigned short* __restrict__ kx,
               const unsigned short* __restrict__ vx, const unsigned short* __restrict__ wq,
               const unsigned short* __restrict__ wk, const unsigned short* __restrict__ wv,
               unsigned short* __restrict__ Qp, unsigned short* __restrict__ Kp,
               unsigned short* __restrict__ VT) {
    __shared__ __align__(16) unsigned short As[128 * 64];
    __shared__ __align__(16) unsigned short Bs[128 * 64];

    const int p = blockIdx.z;
    const unsigned short* X = p == 0 ? qx : p == 1 ? kx : vx;
    const unsigned short* W = p == 0 ? wq : p == 1 ? wk : wv;
    const int bm = blockIdx.y * 128, bn = blockIdx.x * 128;

    f32x4 acc[4][4];
    #pragma unroll
    for (int ms = 0; ms < 4; ++ms)
        #pragma unroll
        for (int ns = 0; ns < 4; ++ns)
            acc[ms][ns] = (f32x4){0.f, 0.f, 0.f, 0.f};

    gemm_kloop128(X, W, As, Bs, bm, bn, acc);

    const int t = threadIdx.x, w = t >> 6, L = t & 63, quad = L >> 4, lm = L & 15;
    const int wr = (w >> 1) * 64, wc = (w & 1) * 64;
    if (p == 2) {
        const int b    = bm >> 11;
        const int s_in = (bm & (SEQ - 1)) + wr;
        #pragma unroll
        for (int ms = 0; ms < 4; ++ms)
            #pragma unroll
            for (int ns = 0; ns < 4; ++ns) {
                int dg = bn + wc + ns * 16 + lm;
                int h  = dg >> 6, d = dg & 63;
                ushort4 pk = make_ushort4(f2bf(acc[ms][ns][0]), f2bf(acc[ms][ns][1]),
                                          f2bf(acc[ms][ns][2]), f2bf(acc[ms][ns][3]));
                *(ushort4*)&VT[((size_t)((b * NHEAD + h) * HDK + d)) * SEQ +
                               s_in + ms * 16 + quad * 4] = pk;
            }
    } else {
        unsigned short* Y = p == 0 ? Qp : Kp;
        // 0.125 * log2(e): softmax runs in exp2 domain (saves a v_mul per exp)
        const float scl = p == 0 ? 0.18033688011112042f : 1.0f;
        #pragma unroll
        for (int ms = 0; ms < 4; ++ms)
            #pragma unroll
            for (int ns = 0; ns < 4; ++ns)
                #pragma unroll
                for (int r = 0; r < 4; ++r)
                    Y[(size_t)(bm + wr + ms * 16 + quad * 4 + r) * D_MODEL +
                      bn + wc + ns * 16 + lm] = f2bf(acc[ms][ns][r] * scl);
    }
}

__global__ __launch_bounds__(256)
void out_gemm(const unsigned short* __restrict__ X, const unsigned short* __restrict__ W,
              float* __restrict__ Y) {
    __shared__ __align__(16) unsigned short As[128 * 64];
    __shared__ __align__(16) unsigned short Bs[64 * 64];
    const int bm = blockIdx.y * 128, bn = blockIdx.x * 64;

    f32x4 acc[2][4];
    #pragma unroll
    for (int ms = 0; ms < 2; ++ms)
        #pragma unroll
        for (int ns = 0; ns < 4; ++ns)
            acc[ms][ns] = (f32x4){0.f, 0.f, 0.f, 0.f};

    gemm_kloop64(X, W, As, Bs, bm, bn, acc);

    const int t = threadIdx.x, w = t >> 6, L = t & 63, quad = L >> 4, lm = L & 15;
    #pragma unroll
    for (int ms = 0; ms < 2; ++ms)
        #pragma unroll
        for (int ns = 0; ns < 4; ++ns)
            #pragma unroll
            for (int r = 0; r < 4; ++r)
                Y[(size_t)(bm + w * 32 + ms * 16 + quad * 4 + r) * D_MODEL +
                  bn + ns * 16 + lm] = acc[ms][ns][r];
}

// ---------------------------------------------------------------------------
// Flash attention, causal, S^T formulation.
// Round-5: uniform-length items via kv-split + combine (flash-decoding).
//  - rows qt>=16 split into two kv-halves (8-16 tiles); rows qt<16 whole
//    (1-16 tiles). 1536 items LPT-ordered by blockIdx; 4/CU residency with
//    backfill -> no 1-block/CU tail (round-4 occupancy 21% was the tail).
//  - split items dump unnormalized partial O (f32, per-thread layout) +
//    per-q (m,l) into dead qb/kb/vb workspace; attn_combine merges.
//  - max-tree via v_max3-fusable triples; tree psum (shorter serial chains).
// ---------------------------------------------------------------------------
__global__ __launch_bounds__(256, 4)
void attn_mfma(const unsigned short* __restrict__ Q, const unsigned short* __restrict__ K,
               const unsigned short* __restrict__ VT, unsigned short* __restrict__ A,
               float* __restrict__ PO, float* __restrict__ PML) {
    __shared__ __align__(16) unsigned short Ks[2][64 * 64];   // [buf][kv][d]  (xor-swizzled)
    __shared__ __align__(16) unsigned short Vs[2][64 * 64];   // [buf][d][kv]  (xor-swizzled)

    const int t    = threadIdx.x;
    const int w    = t >> 6;
    const int L    = t & 63;
    const int quad = L >> 4;
    const int lm   = L & 15;
    const int r8   = L >> 3;
    const int sl   = L & 7;
    const int xcol = (sl ^ r8) * 8;          // pre-swizzled global column for gll16

    // item decode (LPT by blockIdx): [0,1024) = split halves of rows qt>=16,
    // qt descending; [1024,1536) = whole rows qt=15..0.
    const int id = blockIdx.x;
    int qt, bh, k_lo, k_hi, slot;
    if (id < 1024) {
        qt = 31 - (id >> 6);
        const int j    = id & 63;
        const int half = j >> 5;
        bh = j & 31;
        const int c = (qt + 2) >> 1;
        k_lo = half ? c : 0;
        k_hi = half ? qt + 1 : c;
        slot = ((qt - 16) * 32 + bh) * 2 + half;
    } else {
        const int j = id - 1024;
        qt = 15 - (j >> 5);
        bh = j & 31;
        k_lo = 0; k_hi = qt + 1;
        slot = -1;
    }
    const int h = bh & 15;
    const int b = bh >> 4;

    const size_t hb   = (size_t)b * SEQ * D_MODEL + h * HDK;
    const size_t vrow = (size_t)(b * NHEAD + h) * HDK * SEQ;

    const unsigned short* kbase = K + hb;
    const unsigned short* vbase = VT + vrow;

    const int q0   = qt * 64;
    const int qrow = q0 + w * 16 + lm;

    // staging: wave w covers K/V rows (w*2+i)*8 + r8, i in {0,1}
    auto stage = [&](int k0, int buf) {
        #pragma unroll
        for (int i = 0; i < 2; ++i) {
            int row = (w * 2 + i) * 8 + r8;
            gll16(kbase + (size_t)(k0 + row) * D_MODEL + xcol, &Ks[buf][(w * 2 + i) * 512]);
            gll16(vbase + (size_t)row * SEQ + k0 + xcol,       &Vs[buf][(w * 2 + i) * 512]);
        }
    };

    stage(k_lo * 64, 0);

    // Q fragments (B-operand)
    bf16x8 Qf0, Qf1;
    {
        const unsigned short* qp = Q + hb + (size_t)qrow * D_MODEL + quad * 8;
        Qf0 = *(const bf16x8*)qp;
        Qf1 = *(const bf16x8*)(qp + 32);
    }

    f32x4 Oacc[4];
    #pragma unroll
    for (int nt = 0; nt < 4; ++nt) Oacc[nt] = (f32x4){0.f, 0.f, 0.f, 0.f};
    float m_run  = -INFINITY;
    float l_lane = 0.f;                      // per-lane partial; reduced in epilogue

    __syncthreads();                         // drains vmcnt -> first tile staged

    int bb = 0;
    for (int kt = k_lo; kt < k_hi; ++kt) {
        const int k0 = kt * 64;
        const unsigned short* Kc = Ks[bb];
        const unsigned short* Vc = Vs[bb];
        if (kt + 1 < k_hi) stage((kt + 1) * 64, bb ^ 1); // async, drained at iter-end barrier

        // ---- S^T = K Q^T (lane owns q-row lm; kv = ct*16+quad*4+r) ----
        f32x4 S[4];
        __builtin_amdgcn_s_setprio(1);
        #pragma unroll
        for (int ct = 0; ct < 4; ++ct) {
            bf16x8 a0 = *(const bf16x8*)&Kc[(ct * 16 + lm) * 64 + ((quad ^ (lm & 7)) * 8)];
            bf16x8 a1 = *(const bf16x8*)&Kc[(ct * 16 + lm) * 64 + (((4 + quad) ^ (lm & 7)) * 8)];
            f32x4 z = (f32x4){0.f, 0.f, 0.f, 0.f};
            z = __builtin_amdgcn_mfma_f32_16x16x32_bf16(a0, Qf0, z, 0, 0, 0);
            z = __builtin_amdgcn_mfma_f32_16x16x32_bf16(a1, Qf1, z, 0, 0, 0);
            S[ct] = z;
        }
        __builtin_amdgcn_s_setprio(0);

        // causal mask (diag-straddling tiles only; never fires on first-half splits)
        if (k0 + 63 > q0 + w * 16) {
            #pragma unroll
            for (int ct = 0; ct < 4; ++ct)
                #pragma unroll
                for (int r = 0; r < 4; ++r)
                    if ((k0 + ct * 16 + quad * 4 + r) > qrow)
                        S[ct][r] = -1e30f;
        }

        // ---- lane-local online softmax, exp2 domain (max3-fused tree) ----
        float ma = max3(S[0][0], S[0][1], S[0][2]);
        float mb = max3(S[0][3], S[1][0], S[1][1]);
        float mc = max3(S[1][2], S[1][3], S[2][0]);
        float md = max3(S[2][1], S[2][2], S[2][3]);
        float me = max3(S[3][0], S[3][1], S[3][2]);
        float ml = max3(max3(ma, mb, mc), md, me);
        ml = fmaxf(ml, S[3][3]);
        // defer-rescale: cross-lane reduce + O rescale only when a lane's
        // max outgrew the bound (P stays <= 2^8 in f32 accum otherwise).
        if (__any(ml > m_run + 8.0f)) {
            float m = fmaxf(ml, __shfl_xor(ml, 16));
            m = fmaxf(m, __shfl_xor(m, 32));
            const float m_new = fmaxf(m_run, m);
            const float alpha = exp2_fast(m_run - m_new);
            #pragma unroll
            for (int nt = 0; nt < 4; ++nt)
                #pragma unroll
                for (int r = 0; r < 4; ++r) Oacc[nt][r] *= alpha;
            l_lane *= alpha;
            m_run = m_new;
        }
        #pragma unroll
        for (int ct = 0; ct < 4; ++ct)
            #pragma unroll
            for (int r = 0; r < 4; ++r)
                S[ct][r] = exp2_fast(S[ct][r] - m_run);
        // tree psum (short dependency chain)
        {
            float p0 = (S[0][0] + S[0][1]) + (S[0][2] + S[0][3]);
            float p1 = (S[1][0] + S[1][1]) + (S[1][2] + S[1][3]);
            float p2 = (S[2][0] + S[2][1]) + (S[2][2] + S[2][3]);
            float p3 = (S[3][0] + S[3][1]) + (S[3][2] + S[3][3]);
            l_lane += (p0 + p1) + (p2 + p3);
        }

        // ---- P^T -> B-fragments via permlane swaps (no LDS round-trip) ----
        unsigned x0 = pack_hi(S[0][0], S[0][1]);
        unsigned x1 = pack_hi(S[0][2], S[0][3]);
        unsigned y0 = pack_hi(S[1][0], S[1][1]);
        unsigned y1 = pack_hi(S[1][2], S[1][3]);
        asm("v_permlane32_swap_b32 %0, %1" : "+v"(x0), "+v"(y0));
        asm("v_permlane32_swap_b32 %0, %1" : "+v"(x1), "+v"(y1));
        asm("v_permlane16_swap_b32 %0, %1" : "+v"(x0), "+v"(y0));
        asm("v_permlane16_swap_b32 %0, %1" : "+v"(x1), "+v"(y1));
        bf16x8 Pb0 = __builtin_bit_cast(bf16x8, (u32x4){x0, x1, y0, y1});
        unsigned x2 = pack_hi(S[2][0], S[2][1]);
        unsigned x3 = pack_hi(S[2][2], S[2][3]);
        unsigned y2 = pack_hi(S[3][0], S[3][1]);
        unsigned y3 = pack_hi(S[3][2], S[3][3]);
        asm("v_permlane32_swap_b32 %0, %1" : "+v"(x2), "+v"(y2));
        asm("v_permlane32_swap_b32 %0, %1" : "+v"(x3), "+v"(y3));
        asm("v_permlane16_swap_b32 %0, %1" : "+v"(x2), "+v"(y2));
        asm("v_permlane16_swap_b32 %0, %1" : "+v"(x3), "+v"(y3));
        bf16x8 Pb1 = __builtin_bit_cast(bf16x8, (u32x4){x2, x3, y2, y3});

        // ---- O^T += V^T P^T ----
        __builtin_amdgcn_s_setprio(1);
        #pragma unroll
        for (int nt = 0; nt < 4; ++nt) {
            bf16x8 a0 = *(const bf16x8*)&Vc[(nt * 16 + lm) * 64 + ((quad ^ (lm & 7)) * 8)];
            bf16x8 a1 = *(const bf16x8*)&Vc[(nt * 16 + lm) * 64 + (((4 + quad) ^ (lm & 7)) * 8)];
            f32x4 o = Oacc[nt];
            o = __builtin_amdgcn_mfma_f32_16x16x32_bf16(a0, Pb0, o, 0, 0, 0);
            o = __builtin_amdgcn_mfma_f32_16x16x32_bf16(a1, Pb1, o, 0, 0, 0);
            Oacc[nt] = o;
        }
        __builtin_amdgcn_s_setprio(0);

        __syncthreads();                     // buf swap: drains gll16 (vmcnt) + ds
        bb ^= 1;
    }

    // ---- epilogue ----
    float l_row = l_lane + __shfl_xor(l_lane, 16);
    l_row += __shfl_xor(l_row, 32);

    if (slot >= 0) {
        // split item: dump unnormalized partial O (per-thread layout) + (m,l)
        float4* po = (float4*)(PO + (size_t)slot * 4096);
        #pragma unroll
        for (int nt = 0; nt < 4; ++nt)
            po[t * 4 + nt] = __builtin_bit_cast(float4, Oacc[nt]);
        if (quad == 0) {
            PML[slot * 128 + w * 16 + lm]      = m_run;
            PML[slot * 128 + 64 + w * 16 + lm] = l_row;
        }
    } else {
        // whole row: normalize + transpose (Ks[0] dead after loop-end barrier)
        const float inv_l = 1.f / l_row;
        unsigned short* es = &Ks[0][w * 1024];
        #pragma unroll
        for (int nt = 0; nt < 4; ++nt) {
            ushort4 pk = make_ushort4(f2bf(Oacc[nt][0] * inv_l), f2bf(Oacc[nt][1] * inv_l),
                                      f2bf(Oacc[nt][2] * inv_l), f2bf(Oacc[nt][3] * inv_l));
            int lc = 2 * nt + (quad >> 1);
            *(ushort4*)&es[lm * 64 + ((lc ^ (lm & 7)) * 8) + (quad & 1) * 4] = pk;
        }
        #pragma unroll
        for (int pp = 0; pp < 2; ++pp) {
            int qr = pp * 8 + r8;
            int dc = sl * 8;
            uint4 val = *(const uint4*)&es[qr * 64 + ((sl ^ (qr & 7)) * 8)];
            *(uint4*)&A[hb + (size_t)(q0 + w * 16 + qr) * D_MODEL + dc] = val;
        }
    }
}

// ---------------------------------------------------------------------------
// Combine two kv-half partials of one (bh, qt>=16) row: align to max m,
// merge, normalize, write Ap. 512 blocks x 256 thr.
// ---------------------------------------------------------------------------
__global__ __launch_bounds__(256)
void attn_combine(const float* __restrict__ PO, const float* __restrict__ PML,
                  unsigned short* __restrict__ A) {
    __shared__ __align__(16) unsigned short es_[4][16 * 64];

    const int t    = threadIdx.x;
    const int w    = t >> 6;
    const int L    = t & 63;
    const int quad = L >> 4;
    const int lm   = L & 15;
    const int r8   = L >> 3;
    const int sl   = L & 7;

    const int r  = blockIdx.x;               // 0..511
    const int qt = 16 + (r >> 5);
    const int bh = r & 31;
    const int h  = bh & 15;
    const int b  = bh >> 4;
    const size_t hb = (size_t)b * SEQ * D_MODEL + h * HDK;
    const int q0 = qt * 64;
    const int q  = w * 16 + lm;

    const float* ml1 = PML + (size_t)(r * 2 + 0) * 128;
    const float* ml2 = PML + (size_t)(r * 2 + 1) * 128;
    const float m1 = ml1[q], l1 = ml1[64 + q];
    const float m2 = ml2[q], l2 = ml2[64 + q];
    const float M  = fmaxf(m1, m2);
    const float e1 = exp2_fast(m1 - M);
    const float e2 = exp2_fast(m2 - M);
    const float inv = 1.f / (e1 * l1 + e2 * l2);
    const float c1 = e1 * inv, c2 = e2 * inv;

    const float4* o1 = (const float4*)(PO + (size_t)(r * 2 + 0) * 4096);
    const float4* o2 = (const float4*)(PO + (size_t)(r * 2 + 1) * 4096);

    unsigned short* es = &es_[w][0];
    #pragma unroll
    for (int nt = 0; nt < 4; ++nt) {
        float4 a = o1[t * 4 + nt];
        float4 c = o2[t * 4 + nt];
        float v0 = a.x * c1 + c.x * c2;
        float v1 = a.y * c1 + c.y * c2;
        float v2 = a.z * c1 + c.z * c2;
        float v3 = a.w * c1 + c.w * c2;
        ushort4 pk = make_ushort4(f2bf(v0), f2bf(v1), f2bf(v2), f2bf(v3));
        int lc = 2 * nt + (quad >> 1);
        *(ushort4*)&es[lm * 64 + ((lc ^ (lm & 7)) * 8) + (quad & 1) * 4] = pk;
    }
    #pragma unroll
    for (int pp = 0; pp < 2; ++pp) {
        int qr = pp * 8 + r8;
        int dc = sl * 8;
        uint4 val = *(const uint4*)&es[qr * 64 + ((sl ^ (qr & 7)) * 8)];
        *(uint4*)&A[hb + (size_t)(q0 + w * 16 + qr) * D_MODEL + dc] = val;
    }
}

// ---------------------------------------------------------------------------
extern "C" void kernel_launch(void* const* d_in, const int* in_sizes, int n_in,
                              void* d_out, int out_size, void* d_ws, size_t ws_size,
                              hipStream_t stream) {
    const float* q  = (const float*)d_in[0];
    const float* k  = (const float*)d_in[1];
    const float* v  = (const float*)d_in[2];
    const float* Wq = (const float*)d_in[4];
    const float* Wk = (const float*)d_in[5];
    const float* Wv = (const float*)d_in[6];
    const float* Wo = (const float*)d_in[7];
    float* out = (float*)d_out;

    char* ws = (char*)d_ws;
    const size_t MB = 1024 * 1024;
    unsigned short* qb  = (unsigned short*)(ws + 0 * MB);
    unsigned short* kb  = (unsigned short*)(ws + 8 * MB);
    unsigned short* vb  = (unsigned short*)(ws + 16 * MB);
    unsigned short* wqb = (unsigned short*)(ws + 24 * MB);
    unsigned short* wkb = (unsigned short*)(ws + 26 * MB);
    unsigned short* wvb = (unsigned short*)(ws + 28 * MB);
    unsigned short* wob = (unsigned short*)(ws + 30 * MB);
    unsigned short* Qp  = (unsigned short*)(ws + 32 * MB);
    unsigned short* Kp  = (unsigned short*)(ws + 40 * MB);
    unsigned short* VTp = (unsigned short*)(ws + 48 * MB);
    unsigned short* Ap  = (unsigned short*)(ws + 56 * MB);
    // partial buffers overlay qb/kb/vb (dead after proj_gemm)
    float* PO  = (float*)(ws + 0 * MB);      // 1024 slots x 16 KB = 16 MB
    float* PML = (float*)(ws + 16 * MB);     // 1024 slots x 512 B = 512 KB

    const int nX8 = BS * D_MODEL / 8;
    const int nW8 = D_MODEL * D_MODEL / 8;
    cast_act<<<dim3(nX8 / 256, 3), 256, 0, stream>>>(q, k, v, qb, kb, vb, nX8);
    cast_wt <<<dim3(nW8 / 256, 4), 256, 0, stream>>>(Wq, Wk, Wv, Wo, wqb, wkb, wvb, wob, nW8);

    proj_gemm<<<dim3(D_MODEL / 128, BS / 128, 3), 256, 0, stream>>>(
        qb, kb, vb, wqb, wkb, wvb, Qp, Kp, VTp);

    attn_mfma<<<dim3(1536), 256, 0, stream>>>(Qp, Kp, VTp, Ap, PO, PML);
    attn_combine<<<dim3(512), 256, 0, stream>>>(PO, PML, Ap);

    out_gemm<<<dim3(D_MODEL / 64, BS / 128), 256, 0, stream>>>(Ap, wob, out);
}